// Round 18
// baseline (147.922 us; speedup 1.0000x reference)
//
#include <hip/hip_runtime.h>
#include <hip/hip_bf16.h>
#include <math.h>

// mLSTM chunked forward. Round 18: k_intra back to 4 blocks/CU (cross-block
// overlap is the only lever that works for the phase-5 fetch); skip the
// group-first Cp_loc tile (exact zero, pdec==1) on both write and read sides.
// B=4 H=8 T=4096 K=V=128, BT=64, NT=64, GS=8, NG=8.

#define LOG2E 1.4426950408889634f
constexpr int Bsz = 4, Hsz = 8, Tsz = 4096, Ksz = 128, Vsz = 128;
constexpr int BT = 64, NT = 64, BH = Bsz * Hsz;
constexpr float SCALE = 0.08838834764831845f; // 128^-0.5
constexpr int GS = 8, NG = NT / GS;           // chunks per group, groups

typedef __attribute__((ext_vector_type(8))) short short8v;   // MFMA A/B frag (8 bf16)
typedef __attribute__((ext_vector_type(4))) float f32x4;     // MFMA C/D frag
typedef __attribute__((ext_vector_type(4))) unsigned short u16x4;
typedef __attribute__((ext_vector_type(8))) unsigned short u16x8;

__device__ inline float bf2f(unsigned short u) {
    union { unsigned int i; float f; } c; c.i = ((unsigned int)u) << 16; return c.f;
}
__device__ inline unsigned short f2bf(float f) {
    __hip_bfloat16 h = __float2bfloat16(f);            // HW v_cvt (RNE)
    union { __hip_bfloat16 b; unsigned short u; } cv; cv.b = h; return cv.u;
}
__device__ inline float f4c(const float4& v, int y) {
    return y == 0 ? v.x : y == 1 ? v.y : y == 2 ? v.z : v.w;
}

// ---------------- kernel 1: gate preprocessing per (bh, chunk) ----------------
__global__ __launch_bounds__(64) void k_gates(
    const float* __restrict__ ig, const float* __restrict__ fg,
    float* __restrict__ vecB, float* __restrict__ vecI, float* __restrict__ vecA,
    float* __restrict__ mintra, float* __restrict__ scaG, float* __restrict__ scaA)
{
    int c = blockIdx.x, bh = blockIdx.y, lane = threadIdx.x;
    int t = bh * Tsz + c * BT + lane;
    float f = fg[t];
    float ls = fminf(f, 0.f) - log1pf(expf(-fabsf(f)));  // stable log_sigmoid
    float vF = ls * LOG2E;
    float vI = ig[t] * LOG2E;
    float b = vF;
    #pragma unroll
    for (int off = 1; off < 64; off <<= 1) {
        float o = __shfl_up(b, off, 64);
        if (lane >= off) b += o;
    }
    float g = __shfl(b, 63, 64);
    float mi = vI - b;
    #pragma unroll
    for (int off = 1; off < 64; off <<= 1) {
        float o = __shfl_up(mi, off, 64);
        if (lane >= off) mi = fmaxf(mi, o);
    }
    float a = vI + g - b;
    vecB[t] = b; vecI[t] = vI; vecA[t] = a; mintra[t] = b + mi;
    float am = a;
    #pragma unroll
    for (int off = 32; off; off >>= 1) am = fmaxf(am, __shfl_xor(am, off, 64));
    if (lane == 0) { scaG[bh * NT + c] = g; scaA[bh * NT + c] = am; }
}

// ---------------- kernel 2: m scan + dec + pdec (within-group) + decG (per group) ----------------
__global__ __launch_bounds__(64) void k_mscan(
    const float* __restrict__ scaG, const float* __restrict__ scaA,
    float* __restrict__ mp, float* __restrict__ dec,
    float* __restrict__ pdec, float* __restrict__ decG)
{
    int bh = blockIdx.x, lane = threadIdx.x;
    float g0 = scaG[bh * NT + lane];
    float a = g0, b = scaA[bh * NT + lane];
    #pragma unroll
    for (int off = 1; off < 64; off <<= 1) {
        float ap = __shfl_up(a, off, 64);
        float bp = __shfl_up(b, off, 64);
        if (lane >= off) { b = fmaxf(bp + a, b); a = ap + a; }
    }
    float m_incl = fmaxf(a, b);          // m after chunk `lane`
    float m_prev = __shfl_up(m_incl, 1, 64);
    if (lane == 0) { m_prev = 0.f; mp[bh * (NT + 1)] = 0.f; }
    mp[bh * (NT + 1) + lane + 1] = m_incl;
    dec[bh * NT + lane] = exp2f(g0 + m_prev - m_incl);
    float cumE = a - g0;                 // exclusive prefix of g
    int gs = lane & ~(GS - 1);
    float cumE_gs = __shfl(cumE, gs, 64);
    float mp_gs   = __shfl(m_prev, gs, 64);
    pdec[bh * NT + lane] = exp2f(cumE - cumE_gs + mp_gs - m_prev);  // <= 1; ==1 at group start
    // decG[g] = prod of dec over group g (lane<NG)
    int ge = (lane * GS) & 63, gl = (lane * GS + GS - 1) & 63;
    float cumS = __shfl(cumE, ge, 64);
    float mS   = __shfl(m_prev, ge, 64);
    float cumL = __shfl(a, gl, 64);          // inclusive sum through group end
    float mL   = __shfl(m_incl, gl, 64);     // m entering next group
    if (lane < NG) decG[bh * NG + lane] = exp2f(cumL - cumS + mS - mL);
}

// ---------------- kernel 3: fused per-group state scan, V-half split ----------------
__global__ __launch_bounds__(256, 2) void k_state(
    const float* __restrict__ kg, const float* __restrict__ vg,
    const float* __restrict__ vecA, const float* __restrict__ mp,
    const float* __restrict__ dec,
    unsigned short* __restrict__ CpL, unsigned short* __restrict__ Gb,
    float* __restrict__ npl, float* __restrict__ nG)
{
    int g = blockIdx.x, bh = blockIdx.y, vhalf = blockIdx.z, tid = threadIdx.x;
    int c0 = g * GS;
    int lane = tid & 63, wid = tid >> 6;
    int lrow = lane & 15, kgrp = lane >> 4;

    __shared__ __align__(16) unsigned short kT[2][128][72];  // kbar^T, swizzled
    __shared__ __align__(16) unsigned short vT[2][64][72];   // v^T half, swizzled
    __shared__ float nUp[2][128][5];

    int cb = tid & 15, jr = tid >> 4;
    int wboff = (((jr >> 1) ^ (cb & 7)) * 16) + (jr & 1) * 8;
    const float* mpb = mp + bh * (NT + 1);

    float4 kreg[4][2], vreg[4];
    auto issue_loads = [&](int cc) {
        size_t hbc = (size_t)bh * Tsz + (size_t)(c0 + cc) * BT;
        #pragma unroll
        for (int x = 0; x < 4; ++x) {
            #pragma unroll
            for (int p = 0; p < 2; ++p)
                kreg[x][p] = *(const float4*)(kg + (hbc + jr * 4 + x) * Ksz + p * 64 + cb * 4);
            vreg[x] = *(const float4*)(vg + (hbc + jr * 4 + x) * Vsz + vhalf * 64 + cb * 4);
        }
    };
    auto cvt_store = [&](int cc, int bb) {
        size_t hbc = (size_t)bh * Tsz + (size_t)(c0 + cc) * BT;
        float mpn = mpb[c0 + cc + 1];
        float s4[4];
        #pragma unroll
        for (int x = 0; x < 4; ++x) s4[x] = exp2f(vecA[hbc + jr * 4 + x] - mpn);
        #pragma unroll
        for (int p = 0; p < 2; ++p) {
            int cc0 = p * 64 + cb * 4;
            #pragma unroll
            for (int y = 0; y < 4; ++y) {
                u16x4 h;
                float psum = 0.f;
                #pragma unroll
                for (int x = 0; x < 4; ++x) {
                    float kf = f4c(kreg[x][p], y) * s4[x];
                    h[x] = f2bf(kf);
                    psum += kf;
                }
                *(u16x4*)((char*)&kT[bb][cc0 + y][0] + wboff) = h;
                psum += __shfl_xor(psum, 16, 64);
                psum += __shfl_xor(psum, 32, 64);
                if (kgrp == 0) nUp[bb][cc0 + y][wid] = psum;
            }
        }
        #pragma unroll
        for (int y = 0; y < 4; ++y) {
            u16x4 w;
            #pragma unroll
            for (int x = 0; x < 4; ++x) w[x] = f2bf(f4c(vreg[x], y));
            *(u16x4*)((char*)&vT[bb][cb * 4 + y][0] + wboff) = w;
        }
    };

    issue_loads(0);
    cvt_store(0, 0);
    __syncthreads();

    f32x4 acc[2][4];                 // running state C half (fp32)
    #pragma unroll
    for (int kt = 0; kt < 2; ++kt)
        #pragma unroll
        for (int vt = 0; vt < 4; ++vt) acc[kt][vt] = (f32x4){0.f, 0.f, 0.f, 0.f};
    float n_own = 0.f;

    int bb = 0;
    for (int t = 0; t < GS; ++t) {
        if (t + 1 < GS) issue_loads(t + 1);
        int c = c0 + t;
        if (t > 0) {   // t==0 tile is exact zeros; k_intra substitutes B directly
            unsigned short* Cb = CpL + (size_t)(bh * NT + c) * (Ksz * Vsz);
            #pragma unroll
            for (int kt = 0; kt < 2; ++kt) {
                int ktile = wid * 2 + kt;
                #pragma unroll
                for (int vt = 0; vt < 4; ++vt) {
                    u16x4 w;
                    #pragma unroll
                    for (int r = 0; r < 4; ++r) w[r] = f2bf(acc[kt][vt][r]);
                    *(u16x4*)(Cb + ((size_t)(ktile * 8 + vhalf * 4 + vt) * 64 + lane) * 4) = w;
                }
            }
        }
        if (vhalf == 0 && tid < Ksz) npl[(size_t)(bh * NT + c) * Ksz + tid] = n_own;
        float dct = dec[bh * NT + c];
        #pragma unroll
        for (int kt = 0; kt < 2; ++kt)
            #pragma unroll
            for (int vt = 0; vt < 4; ++vt)
                #pragma unroll
                for (int r = 0; r < 4; ++r) acc[kt][vt][r] *= dct;
        #pragma unroll
        for (int ks = 0; ks < 2; ++ks) {
            int G2 = ks * 4 + kgrp;
            #pragma unroll
            for (int kt = 0; kt < 2; ++kt) {
                int arow = (wid * 2 + kt) * 16 + lrow;
                short8v af = *(const short8v*)((const char*)&kT[bb][arow][0]
                                               + ((G2 ^ ((arow >> 2) & 7)) * 16));
                #pragma unroll
                for (int vt = 0; vt < 4; ++vt) {
                    int brow = vt * 16 + lrow;
                    short8v bv = *(const short8v*)((const char*)&vT[bb][brow][0]
                                                   + ((G2 ^ ((brow >> 2) & 7)) * 16));
                    acc[kt][vt] = __builtin_amdgcn_mfma_f32_16x16x32_bf16(af, bv, acc[kt][vt], 0, 0, 0);
                }
            }
        }
        if (tid < Ksz) {
            float s = nUp[bb][tid][0] + nUp[bb][tid][1] + nUp[bb][tid][2] + nUp[bb][tid][3];
            n_own = n_own * dct + s;
        }
        if (t + 1 < GS) {
            cvt_store(t + 1, bb ^ 1);
            __syncthreads();
            bb ^= 1;
        }
    }
    unsigned short* Gg = Gb + (size_t)(bh * NG + g) * (Ksz * Vsz);
    #pragma unroll
    for (int kt = 0; kt < 2; ++kt) {
        int ktile = wid * 2 + kt;
        #pragma unroll
        for (int vt = 0; vt < 4; ++vt) {
            u16x4 w;
            #pragma unroll
            for (int r = 0; r < 4; ++r) w[r] = f2bf(acc[kt][vt][r]);
            *(u16x4*)(Gg + ((size_t)(ktile * 8 + vhalf * 4 + vt) * 64 + lane) * 4) = w;
        }
    }
    if (vhalf == 0 && tid < Ksz) nG[(size_t)(bh * NG + g) * Ksz + tid] = n_own;
}

// ---------------- kernel 4: group-total scan, in place (G -> B, nG -> nB) ----------------
__global__ __launch_bounds__(128) void k_gscan(
    unsigned short* __restrict__ Gb, float* __restrict__ nG,
    const float* __restrict__ decG)
{
    int s = blockIdx.x, bh = blockIdx.y, tid = threadIdx.x;
    __shared__ float dgs[NG];
    if (tid < NG) dgs[tid] = decG[bh * NG + tid];
    __syncthreads();
    if (s == 32) {   // n scan
        float n = 0.f;
        size_t base = (size_t)bh * NG * Ksz + tid;
        #pragma unroll
        for (int g = 0; g < NG; ++g) {
            float u = nG[base + (size_t)g * Ksz];
            nG[base + (size_t)g * Ksz] = n;
            n = n * dgs[g] + u;
        }
        return;
    }
    size_t base = (size_t)bh * NG * (Ksz * Vsz) + s * 512 + tid * 4;
    float C0 = 0.f, C1 = 0.f, C2 = 0.f, C3 = 0.f;
    #pragma unroll
    for (int g = 0; g < NG; ++g) {
        size_t idx = base + (size_t)g * (Ksz * Vsz);
        u16x4 u = *(const u16x4*)(Gb + idx);
        u16x4 w;
        w.x = f2bf(C0); w.y = f2bf(C1); w.z = f2bf(C2); w.w = f2bf(C3);
        *(u16x4*)(Gb + idx) = w;
        float d = dgs[g];
        C0 = C0 * d + bf2f(u.x); C1 = C1 * d + bf2f(u.y);
        C2 = C2 * d + bf2f(u.z); C3 = C3 * d + bf2f(u.w);
    }
}

// ---------------- kernel 5: intra + consumption + normalize ----------------
// Phased LDS reuse {khi,klo} -> {Sb,vT} -> {Cp_eff}, 36.8 KB -> 4 blocks/CU.
// Group-first chunks (c%GS==0): Cp_eff = B exactly (pdec==1, Cp_loc==0) -> skip cpre.
__global__ __launch_bounds__(256, 4) void k_intra(
    const float* __restrict__ qg, const float* __restrict__ kgl, const float* __restrict__ vg,
    const float* __restrict__ vecB, const float* __restrict__ vecI,
    const float* __restrict__ mintra, const float* __restrict__ mp,
    const float* __restrict__ npl, const float* __restrict__ nB,
    const unsigned short* __restrict__ CpL, const unsigned short* __restrict__ Bb,
    const float* __restrict__ pdec, float* __restrict__ out)
{
    int b0 = blockIdx.x, bh = blockIdx.y, tid = threadIdx.x;
    int c = ((b0 & 7) << 3) | (b0 >> 3);   // group-affine XCD remap (bijective on [0,64))
    int lane = tid & 63, wid = tid >> 6;
    int lrow = lane & 15, kgrp = lane >> 4;
    int grp = c / GS;
    bool firstc = (c & (GS - 1)) == 0;

    __shared__ __align__(16) unsigned short R[17408];   // 34816 B, phase-shared
    __shared__ float rowf[BT], colf[BT], sfqs[BT], emcs[BT], denb[BT], npv[Ksz];

    auto khi = (unsigned short(*)[136])R;
    auto klo = (unsigned short(*)[136])(R + 64 * 136);
    auto Sb  = (unsigned short(*)[72])R;
    unsigned short* vTf = R + 64 * 72;
    unsigned short* cpsF = R;

    size_t hb = (size_t)bh * Tsz + (size_t)c * BT;
    float mpc = mp[bh * (NT + 1) + c];
    float pd = pdec[bh * NT + c];
    if (tid < BT) {
        float b = vecB[hb + tid];
        float mc = fmaxf(mpc + b, mintra[hb + tid]);
        rowf[tid] = SCALE * exp2f(b - mc);
        colf[tid] = exp2f(vecI[hb + tid] - b);
        sfqs[tid] = SCALE * exp2f(b + mpc - mc);
        emcs[tid] = exp2f(-mc);
    }
    if (tid < Ksz)
        npv[tid] = npl[((size_t)bh * NT + c) * Ksz + tid]
                 + pd * nB[((size_t)bh * NG + grp) * Ksz + tid];

    // ---- phase 1: stage k hi/lo; q -> regs; v prefetch ----
    const float4* k4 = (const float4*)(kgl + hb * Ksz);
    for (int e = tid; e < BT * Ksz / 4; e += 256) {
        int i = e >> 5, c4 = (e & 31) * 4;
        float4 kv = k4[e];
        u16x4 h, l;
        h.x = f2bf(kv.x); l.x = f2bf(kv.x - bf2f(h.x));
        h.y = f2bf(kv.y); l.y = f2bf(kv.y - bf2f(h.y));
        h.z = f2bf(kv.z); l.z = f2bf(kv.z - bf2f(h.z));
        h.w = f2bf(kv.w); l.w = f2bf(kv.w - bf2f(h.w));
        *(u16x4*)&khi[i][c4] = h; *(u16x4*)&klo[i][c4] = l;
    }
    const float* qrow = qg + (hb + wid * 16 + lrow) * Ksz;
    float qf[4][8];
    #pragma unroll
    for (int ks = 0; ks < 4; ++ks) {
        float4 a = *(const float4*)(qrow + ks * 32 + kgrp * 8);
        float4 b = *(const float4*)(qrow + ks * 32 + kgrp * 8 + 4);
        qf[ks][0] = a.x; qf[ks][1] = a.y; qf[ks][2] = a.z; qf[ks][3] = a.w;
        qf[ks][4] = b.x; qf[ks][5] = b.y; qf[ks][6] = b.z; qf[ks][7] = b.w;
    }
    int vcb = tid & 15, jb = tid >> 4;
    float vpre[2][4][4];
    #pragma unroll
    for (int p = 0; p < 2; ++p)
        #pragma unroll
        for (int x = 0; x < 4; ++x) {
            float4 r4 = *(const float4*)(vg + (hb + jb * 4 + x) * Vsz + p * 64 + vcb * 4);
            vpre[p][x][0] = r4.x; vpre[p][x][1] = r4.y; vpre[p][x][2] = r4.z; vpre[p][x][3] = r4.w;
        }
    __syncthreads();

    // ---- phase 2: denominator inter part + S = q k^T (3-way split) ----
    float dot = 0.f;
    #pragma unroll
    for (int ks = 0; ks < 4; ++ks)
        #pragma unroll
        for (int x = 0; x < 8; ++x) dot += qf[ks][x] * npv[ks * 32 + kgrp * 8 + x];
    dot += __shfl_xor(dot, 16, 64);
    dot += __shfl_xor(dot, 32, 64);
    float qdot = sfqs[wid * 16 + lrow] * dot;

    short8v qh[4], ql[4];
    #pragma unroll
    for (int ks = 0; ks < 4; ++ks)
        #pragma unroll
        for (int x = 0; x < 8; ++x) {
            float f = qf[ks][x];
            unsigned short hh = f2bf(f);
            qh[ks][x] = (short)hh;
            ql[ks][x] = (short)f2bf(f - bf2f(hh));
        }

    f32x4 accS[4];
    #pragma unroll
    for (int jt = 0; jt < 4; ++jt) accS[jt] = (f32x4){0.f, 0.f, 0.f, 0.f};
    #pragma unroll
    for (int ks = 0; ks < 4; ++ks) {
        #pragma unroll
        for (int jt = 0; jt < 4; ++jt) {
            if (jt <= wid) {
                short8v bh_ = *(const short8v*)&khi[jt * 16 + lrow][ks * 32 + kgrp * 8];
                short8v bl  = *(const short8v*)&klo[jt * 16 + lrow][ks * 32 + kgrp * 8];
                accS[jt] = __builtin_amdgcn_mfma_f32_16x16x32_bf16(qh[ks], bh_, accS[jt], 0, 0, 0);
                accS[jt] = __builtin_amdgcn_mfma_f32_16x16x32_bf16(ql[ks], bh_, accS[jt], 0, 0, 0);
                accS[jt] = __builtin_amdgcn_mfma_f32_16x16x32_bf16(qh[ks], bl,  accS[jt], 0, 0, 0);
            }
        }
    }

    float rsum[4] = {0.f, 0.f, 0.f, 0.f};
    unsigned short sreg[4][4];
    #pragma unroll
    for (int jt = 0; jt < 4; ++jt)
        #pragma unroll
        for (int r = 0; r < 4; ++r) {
            int i = wid * 16 + kgrp * 4 + r, j = jt * 16 + lrow;
            float val = (j <= i) ? accS[jt][r] * rowf[i] * colf[j] : 0.f;
            rsum[r] += val;
            sreg[jt][r] = f2bf(val);
        }
    #pragma unroll
    for (int r = 0; r < 4; ++r) {
        rsum[r] += __shfl_xor(rsum[r], 1, 64);
        rsum[r] += __shfl_xor(rsum[r], 2, 64);
        rsum[r] += __shfl_xor(rsum[r], 4, 64);
        rsum[r] += __shfl_xor(rsum[r], 8, 64);
    }
    float qd[4];
    #pragma unroll
    for (int r = 0; r < 4; ++r) qd[r] = __shfl(qdot, kgrp * 4 + r, 64);
    if (lrow == 0) {
        #pragma unroll
        for (int r = 0; r < 4; ++r) {
            int i = wid * 16 + kgrp * 4 + r;
            float den = qd[r] + rsum[r];
            denb[i] = 1.f / fmaxf(fabsf(den), emcs[i]);
        }
    }
    __syncthreads();   // phase-A reads of khi/klo complete

    // ---- phase 3: issue Cp/B loads; write Sb + swizzled vT ----
    const u16x8* Cg = (const u16x8*)(CpL + ((size_t)bh * NT + c) * (Ksz * Vsz));
    const u16x8* Bg = (const u16x8*)(Bb + ((size_t)bh * NG + grp) * (Ksz * Vsz));
    u16x8 cpre[8], bpre[8];
    #pragma unroll
    for (int p2 = 0; p2 < 8; ++p2) bpre[p2] = Bg[tid + p2 * 256];
    if (!firstc) {
        #pragma unroll
        for (int p2 = 0; p2 < 8; ++p2) cpre[p2] = Cg[tid + p2 * 256];
    }

    #pragma unroll
    for (int jt = 0; jt < 4; ++jt)
        #pragma unroll
        for (int r = 0; r < 4; ++r)
            Sb[wid * 16 + kgrp * 4 + r][jt * 16 + lrow] = sreg[jt][r];
    #pragma unroll
    for (int p = 0; p < 2; ++p)
        #pragma unroll
        for (int y = 0; y < 4; ++y) {
            int row = p * 64 + vcb * 4 + y;
            int swzb = (jb * 8) ^ ((row & 7) << 4);
            u16x4 w;
            #pragma unroll
            for (int x = 0; x < 4; ++x) w[x] = f2bf(vpre[p][x][y]);
            *(u16x4*)((char*)(vTf + row * 64) + swzb) = w;
        }
    __syncthreads();

    // ---- phase 4: PV = S @ v ----
    f32x4 accV[8];
    #pragma unroll
    for (int vt = 0; vt < 8; ++vt) accV[vt] = (f32x4){0.f, 0.f, 0.f, 0.f};
    #pragma unroll
    for (int ks = 0; ks < 2; ++ks) {
        short8v as_ = *(const short8v*)&Sb[wid * 16 + lrow][ks * 32 + kgrp * 8];
        #pragma unroll
        for (int vt = 0; vt < 8; ++vt) {
            int row = vt * 16 + lrow;
            int swzb = ((ks * 64 + kgrp * 16)) ^ ((row & 7) << 4);
            short8v bv = *(const short8v*)((const char*)(vTf + row * 64) + swzb);
            accV[vt] = __builtin_amdgcn_mfma_f32_16x16x32_bf16(as_, bv, accV[vt], 0, 0, 0);
        }
    }
    __syncthreads();   // phase-B reads of Sb/vT complete

    // ---- phase 5: stage Cp_eff = Cp_loc + pd*B (or B exactly for group-first chunk) ----
    if (firstc) {
        #pragma unroll
        for (int p2 = 0; p2 < 8; ++p2) {
            int idx = tid + p2 * 256;
            *(u16x8*)&cpsF[idx * 8] = bpre[p2];   // pd==1, Cp_loc==0 -> Cp_eff = B
        }
    } else {
        #pragma unroll
        for (int p2 = 0; p2 < 8; ++p2) {
            int idx = tid + p2 * 256;
            u16x8 cv = cpre[p2], bv = bpre[p2];
            u16x8 w;
            #pragma unroll
            for (int e = 0; e < 8; ++e) w[e] = f2bf(bf2f(cv[e]) + pd * bf2f(bv[e]));
            *(u16x8*)&cpsF[idx * 8] = w;
        }
    }
    __syncthreads();

    // ---- phase 6: inter = q @ Cp_eff + combine + store ----
    f32x4 accC[8];
    #pragma unroll
    for (int vt = 0; vt < 8; ++vt) accC[vt] = (f32x4){0.f, 0.f, 0.f, 0.f};
    #pragma unroll
    for (int ks = 0; ks < 4; ++ks) {
        int ktile = ks * 2 + (kgrp >> 1);
        int lsrc = (kgrp & 1) * 32 + lrow;
        #pragma unroll
        for (int vt = 0; vt < 8; ++vt) {
            const unsigned short* pf = &cpsF[((ktile * 8 + vt) * 64 + lsrc) * 4];
            u16x4 lo4 = *(const u16x4*)pf;
            u16x4 hi4 = *(const u16x4*)(pf + 64);
            short8v bc;
            bc[0] = (short)lo4.x; bc[1] = (short)lo4.y; bc[2] = (short)lo4.z; bc[3] = (short)lo4.w;
            bc[4] = (short)hi4.x; bc[5] = (short)hi4.y; bc[6] = (short)hi4.z; bc[7] = (short)hi4.w;
            accC[vt] = __builtin_amdgcn_mfma_f32_16x16x32_bf16(qh[ks], bc, accC[vt], 0, 0, 0);
            accC[vt] = __builtin_amdgcn_mfma_f32_16x16x32_bf16(ql[ks], bc, accC[vt], 0, 0, 0);
        }
    }
    size_t gb = hb * Vsz;
    #pragma unroll
    for (int vt = 0; vt < 8; ++vt)
        #pragma unroll
        for (int r = 0; r < 4; ++r) {
            int i = wid * 16 + kgrp * 4 + r, vc = vt * 16 + lrow;
            out[gb + (size_t)i * Vsz + vc] = (sfqs[i] * accC[vt][r] + accV[vt][r]) * denb[i];
        }
}

extern "C" void kernel_launch(void* const* d_in, const int* in_sizes, int n_in,
                              void* d_out, int out_size, void* d_ws, size_t ws_size,
                              hipStream_t stream) {
    const float* q  = (const float*)d_in[0];
    const float* k  = (const float*)d_in[1];
    const float* v  = (const float*)d_in[2];
    const float* ig = (const float*)d_in[3];
    const float* fg = (const float*)d_in[4];
    float* out = (float*)d_out;

    float* ws = (float*)d_ws;
    float* vecB   = ws;                       // BH*T
    float* vecI   = vecB + BH * Tsz;          // BH*T
    float* vecA   = vecI + BH * Tsz;          // BH*T
    float* mintra = vecA + BH * Tsz;          // BH*T
    float* scaG   = mintra + BH * Tsz;        // BH*NT
    float* scaA   = scaG + BH * NT;           // BH*NT
    float* dec    = scaA + BH * NT;           // BH*NT
    float* pdec   = dec + BH * NT;            // BH*NT
    float* decG   = pdec + BH * NT;           // BH*NG
    float* mp     = decG + BH * NG;           // BH*(NT+1)
    float* npl    = mp + BH * (NT + 1);       // BH*NT*K
    float* nG     = npl + BH * NT * Ksz;      // BH*NG*K
    unsigned short* CpL = (unsigned short*)(nG + BH * NG * Ksz);  // BH*NT*K*V bf16
    unsigned short* Gb  = CpL + (size_t)BH * NT * Ksz * Vsz;      // BH*NG*K*V bf16

    k_gates<<<dim3(NT, BH), 64, 0, stream>>>(ig, fg, vecB, vecI, vecA, mintra, scaG, scaA);
    k_mscan<<<dim3(BH), 64, 0, stream>>>(scaG, scaA, mp, dec, pdec, decG);
    k_state<<<dim3(NG, BH, 2), 256, 0, stream>>>(k, v, vecA, mp, dec, CpL, Gb, npl, nG);
    k_gscan<<<dim3(33, BH), 128, 0, stream>>>(Gb, nG, decG);
    k_intra<<<dim3(NT, BH), 256, 0, stream>>>(q, k, v, vecB, vecI, mintra, mp,
                                              npl, nG, CpL, Gb, pdec, out);
}

// Round 19
// 112.017 us; speedup vs baseline: 1.3205x; 1.3205x over previous
//
#include <hip/hip_runtime.h>
#include <hip/hip_bf16.h>
#include <math.h>

// mLSTM chunked forward. Round 19: r15/r17 proven config (k_intra launch_bounds(256,2),
// 36.8KB phased LDS) + zero-tile skip (group-first Cp_loc is exact zero, pdec==1:
// k_state skips the store, k_intra skips the load and stages Cp_eff=B directly).
// B=4 H=8 T=4096 K=V=128, BT=64, NT=64, GS=8, NG=8.

#define LOG2E 1.4426950408889634f
constexpr int Bsz = 4, Hsz = 8, Tsz = 4096, Ksz = 128, Vsz = 128;
constexpr int BT = 64, NT = 64, BH = Bsz * Hsz;
constexpr float SCALE = 0.08838834764831845f; // 128^-0.5
constexpr int GS = 8, NG = NT / GS;           // chunks per group, groups

typedef __attribute__((ext_vector_type(8))) short short8v;   // MFMA A/B frag (8 bf16)
typedef __attribute__((ext_vector_type(4))) float f32x4;     // MFMA C/D frag
typedef __attribute__((ext_vector_type(4))) unsigned short u16x4;
typedef __attribute__((ext_vector_type(8))) unsigned short u16x8;

__device__ inline float bf2f(unsigned short u) {
    union { unsigned int i; float f; } c; c.i = ((unsigned int)u) << 16; return c.f;
}
__device__ inline unsigned short f2bf(float f) {
    __hip_bfloat16 h = __float2bfloat16(f);            // HW v_cvt (RNE)
    union { __hip_bfloat16 b; unsigned short u; } cv; cv.b = h; return cv.u;
}
__device__ inline float f4c(const float4& v, int y) {
    return y == 0 ? v.x : y == 1 ? v.y : y == 2 ? v.z : v.w;
}

// ---------------- kernel 1: gate preprocessing per (bh, chunk) ----------------
__global__ __launch_bounds__(64) void k_gates(
    const float* __restrict__ ig, const float* __restrict__ fg,
    float* __restrict__ vecB, float* __restrict__ vecI, float* __restrict__ vecA,
    float* __restrict__ mintra, float* __restrict__ scaG, float* __restrict__ scaA)
{
    int c = blockIdx.x, bh = blockIdx.y, lane = threadIdx.x;
    int t = bh * Tsz + c * BT + lane;
    float f = fg[t];
    float ls = fminf(f, 0.f) - log1pf(expf(-fabsf(f)));  // stable log_sigmoid
    float vF = ls * LOG2E;
    float vI = ig[t] * LOG2E;
    float b = vF;
    #pragma unroll
    for (int off = 1; off < 64; off <<= 1) {
        float o = __shfl_up(b, off, 64);
        if (lane >= off) b += o;
    }
    float g = __shfl(b, 63, 64);
    float mi = vI - b;
    #pragma unroll
    for (int off = 1; off < 64; off <<= 1) {
        float o = __shfl_up(mi, off, 64);
        if (lane >= off) mi = fmaxf(mi, o);
    }
    float a = vI + g - b;
    vecB[t] = b; vecI[t] = vI; vecA[t] = a; mintra[t] = b + mi;
    float am = a;
    #pragma unroll
    for (int off = 32; off; off >>= 1) am = fmaxf(am, __shfl_xor(am, off, 64));
    if (lane == 0) { scaG[bh * NT + c] = g; scaA[bh * NT + c] = am; }
}

// ---------------- kernel 2: m scan + dec + pdec (within-group) + decG (per group) ----------------
__global__ __launch_bounds__(64) void k_mscan(
    const float* __restrict__ scaG, const float* __restrict__ scaA,
    float* __restrict__ mp, float* __restrict__ dec,
    float* __restrict__ pdec, float* __restrict__ decG)
{
    int bh = blockIdx.x, lane = threadIdx.x;
    float g0 = scaG[bh * NT + lane];
    float a = g0, b = scaA[bh * NT + lane];
    #pragma unroll
    for (int off = 1; off < 64; off <<= 1) {
        float ap = __shfl_up(a, off, 64);
        float bp = __shfl_up(b, off, 64);
        if (lane >= off) { b = fmaxf(bp + a, b); a = ap + a; }
    }
    float m_incl = fmaxf(a, b);          // m after chunk `lane`
    float m_prev = __shfl_up(m_incl, 1, 64);
    if (lane == 0) { m_prev = 0.f; mp[bh * (NT + 1)] = 0.f; }
    mp[bh * (NT + 1) + lane + 1] = m_incl;
    dec[bh * NT + lane] = exp2f(g0 + m_prev - m_incl);
    float cumE = a - g0;                 // exclusive prefix of g
    int gs = lane & ~(GS - 1);
    float cumE_gs = __shfl(cumE, gs, 64);
    float mp_gs   = __shfl(m_prev, gs, 64);
    pdec[bh * NT + lane] = exp2f(cumE - cumE_gs + mp_gs - m_prev);  // <= 1; ==1 at group start
    // decG[g] = prod of dec over group g (lane<NG)
    int ge = (lane * GS) & 63, gl = (lane * GS + GS - 1) & 63;
    float cumS = __shfl(cumE, ge, 64);
    float mS   = __shfl(m_prev, ge, 64);
    float cumL = __shfl(a, gl, 64);          // inclusive sum through group end
    float mL   = __shfl(m_incl, gl, 64);     // m entering next group
    if (lane < NG) decG[bh * NG + lane] = exp2f(cumL - cumS + mS - mL);
}

// ---------------- kernel 3: fused per-group state scan, V-half split ----------------
__global__ __launch_bounds__(256, 2) void k_state(
    const float* __restrict__ kg, const float* __restrict__ vg,
    const float* __restrict__ vecA, const float* __restrict__ mp,
    const float* __restrict__ dec,
    unsigned short* __restrict__ CpL, unsigned short* __restrict__ Gb,
    float* __restrict__ npl, float* __restrict__ nG)
{
    int g = blockIdx.x, bh = blockIdx.y, vhalf = blockIdx.z, tid = threadIdx.x;
    int c0 = g * GS;
    int lane = tid & 63, wid = tid >> 6;
    int lrow = lane & 15, kgrp = lane >> 4;

    __shared__ __align__(16) unsigned short kT[2][128][72];  // kbar^T, swizzled
    __shared__ __align__(16) unsigned short vT[2][64][72];   // v^T half, swizzled
    __shared__ float nUp[2][128][5];

    int cb = tid & 15, jr = tid >> 4;
    int wboff = (((jr >> 1) ^ (cb & 7)) * 16) + (jr & 1) * 8;
    const float* mpb = mp + bh * (NT + 1);

    float4 kreg[4][2], vreg[4];
    auto issue_loads = [&](int cc) {
        size_t hbc = (size_t)bh * Tsz + (size_t)(c0 + cc) * BT;
        #pragma unroll
        for (int x = 0; x < 4; ++x) {
            #pragma unroll
            for (int p = 0; p < 2; ++p)
                kreg[x][p] = *(const float4*)(kg + (hbc + jr * 4 + x) * Ksz + p * 64 + cb * 4);
            vreg[x] = *(const float4*)(vg + (hbc + jr * 4 + x) * Vsz + vhalf * 64 + cb * 4);
        }
    };
    auto cvt_store = [&](int cc, int bb) {
        size_t hbc = (size_t)bh * Tsz + (size_t)(c0 + cc) * BT;
        float mpn = mpb[c0 + cc + 1];
        float s4[4];
        #pragma unroll
        for (int x = 0; x < 4; ++x) s4[x] = exp2f(vecA[hbc + jr * 4 + x] - mpn);
        #pragma unroll
        for (int p = 0; p < 2; ++p) {
            int cc0 = p * 64 + cb * 4;
            #pragma unroll
            for (int y = 0; y < 4; ++y) {
                u16x4 h;
                float psum = 0.f;
                #pragma unroll
                for (int x = 0; x < 4; ++x) {
                    float kf = f4c(kreg[x][p], y) * s4[x];
                    h[x] = f2bf(kf);
                    psum += kf;
                }
                *(u16x4*)((char*)&kT[bb][cc0 + y][0] + wboff) = h;
                psum += __shfl_xor(psum, 16, 64);
                psum += __shfl_xor(psum, 32, 64);
                if (kgrp == 0) nUp[bb][cc0 + y][wid] = psum;
            }
        }
        #pragma unroll
        for (int y = 0; y < 4; ++y) {
            u16x4 w;
            #pragma unroll
            for (int x = 0; x < 4; ++x) w[x] = f2bf(f4c(vreg[x], y));
            *(u16x4*)((char*)&vT[bb][cb * 4 + y][0] + wboff) = w;
        }
    };

    issue_loads(0);
    cvt_store(0, 0);
    __syncthreads();

    f32x4 acc[2][4];                 // running state C half (fp32)
    #pragma unroll
    for (int kt = 0; kt < 2; ++kt)
        #pragma unroll
        for (int vt = 0; vt < 4; ++vt) acc[kt][vt] = (f32x4){0.f, 0.f, 0.f, 0.f};
    float n_own = 0.f;

    int bb = 0;
    for (int t = 0; t < GS; ++t) {
        if (t + 1 < GS) issue_loads(t + 1);
        int c = c0 + t;
        if (t > 0) {   // t==0 tile is exact zeros; k_intra substitutes B directly
            unsigned short* Cb = CpL + (size_t)(bh * NT + c) * (Ksz * Vsz);
            #pragma unroll
            for (int kt = 0; kt < 2; ++kt) {
                int ktile = wid * 2 + kt;
                #pragma unroll
                for (int vt = 0; vt < 4; ++vt) {
                    u16x4 w;
                    #pragma unroll
                    for (int r = 0; r < 4; ++r) w[r] = f2bf(acc[kt][vt][r]);
                    *(u16x4*)(Cb + ((size_t)(ktile * 8 + vhalf * 4 + vt) * 64 + lane) * 4) = w;
                }
            }
        }
        if (vhalf == 0 && tid < Ksz) npl[(size_t)(bh * NT + c) * Ksz + tid] = n_own;
        float dct = dec[bh * NT + c];
        #pragma unroll
        for (int kt = 0; kt < 2; ++kt)
            #pragma unroll
            for (int vt = 0; vt < 4; ++vt)
                #pragma unroll
                for (int r = 0; r < 4; ++r) acc[kt][vt][r] *= dct;
        #pragma unroll
        for (int ks = 0; ks < 2; ++ks) {
            int G2 = ks * 4 + kgrp;
            #pragma unroll
            for (int kt = 0; kt < 2; ++kt) {
                int arow = (wid * 2 + kt) * 16 + lrow;
                short8v af = *(const short8v*)((const char*)&kT[bb][arow][0]
                                               + ((G2 ^ ((arow >> 2) & 7)) * 16));
                #pragma unroll
                for (int vt = 0; vt < 4; ++vt) {
                    int brow = vt * 16 + lrow;
                    short8v bv = *(const short8v*)((const char*)&vT[bb][brow][0]
                                                   + ((G2 ^ ((brow >> 2) & 7)) * 16));
                    acc[kt][vt] = __builtin_amdgcn_mfma_f32_16x16x32_bf16(af, bv, acc[kt][vt], 0, 0, 0);
                }
            }
        }
        if (tid < Ksz) {
            float s = nUp[bb][tid][0] + nUp[bb][tid][1] + nUp[bb][tid][2] + nUp[bb][tid][3];
            n_own = n_own * dct + s;
        }
        if (t + 1 < GS) {
            cvt_store(t + 1, bb ^ 1);
            __syncthreads();
            bb ^= 1;
        }
    }
    unsigned short* Gg = Gb + (size_t)(bh * NG + g) * (Ksz * Vsz);
    #pragma unroll
    for (int kt = 0; kt < 2; ++kt) {
        int ktile = wid * 2 + kt;
        #pragma unroll
        for (int vt = 0; vt < 4; ++vt) {
            u16x4 w;
            #pragma unroll
            for (int r = 0; r < 4; ++r) w[r] = f2bf(acc[kt][vt][r]);
            *(u16x4*)(Gg + ((size_t)(ktile * 8 + vhalf * 4 + vt) * 64 + lane) * 4) = w;
        }
    }
    if (vhalf == 0 && tid < Ksz) nG[(size_t)(bh * NG + g) * Ksz + tid] = n_own;
}

// ---------------- kernel 4: group-total scan, in place (G -> B, nG -> nB) ----------------
__global__ __launch_bounds__(128) void k_gscan(
    unsigned short* __restrict__ Gb, float* __restrict__ nG,
    const float* __restrict__ decG)
{
    int s = blockIdx.x, bh = blockIdx.y, tid = threadIdx.x;
    __shared__ float dgs[NG];
    if (tid < NG) dgs[tid] = decG[bh * NG + tid];
    __syncthreads();
    if (s == 32) {   // n scan
        float n = 0.f;
        size_t base = (size_t)bh * NG * Ksz + tid;
        #pragma unroll
        for (int g = 0; g < NG; ++g) {
            float u = nG[base + (size_t)g * Ksz];
            nG[base + (size_t)g * Ksz] = n;
            n = n * dgs[g] + u;
        }
        return;
    }
    size_t base = (size_t)bh * NG * (Ksz * Vsz) + s * 512 + tid * 4;
    float C0 = 0.f, C1 = 0.f, C2 = 0.f, C3 = 0.f;
    #pragma unroll
    for (int g = 0; g < NG; ++g) {
        size_t idx = base + (size_t)g * (Ksz * Vsz);
        u16x4 u = *(const u16x4*)(Gb + idx);
        u16x4 w;
        w.x = f2bf(C0); w.y = f2bf(C1); w.z = f2bf(C2); w.w = f2bf(C3);
        *(u16x4*)(Gb + idx) = w;
        float d = dgs[g];
        C0 = C0 * d + bf2f(u.x); C1 = C1 * d + bf2f(u.y);
        C2 = C2 * d + bf2f(u.z); C3 = C3 * d + bf2f(u.w);
    }
}

// ---------------- kernel 5: intra + consumption + normalize ----------------
// Phased LDS reuse {khi,klo} -> {Sb,vT} -> {Cp_eff}, 36.8 KB, launch_bounds(256,2).
// Group-first chunks (c%GS==0): Cp_eff = B exactly (pdec==1, Cp_loc==0) -> skip cpre.
__global__ __launch_bounds__(256, 2) void k_intra(
    const float* __restrict__ qg, const float* __restrict__ kgl, const float* __restrict__ vg,
    const float* __restrict__ vecB, const float* __restrict__ vecI,
    const float* __restrict__ mintra, const float* __restrict__ mp,
    const float* __restrict__ npl, const float* __restrict__ nB,
    const unsigned short* __restrict__ CpL, const unsigned short* __restrict__ Bb,
    const float* __restrict__ pdec, float* __restrict__ out)
{
    int b0 = blockIdx.x, bh = blockIdx.y, tid = threadIdx.x;
    int c = ((b0 & 7) << 3) | (b0 >> 3);   // group-affine XCD remap (bijective on [0,64))
    int lane = tid & 63, wid = tid >> 6;
    int lrow = lane & 15, kgrp = lane >> 4;
    int grp = c / GS;
    bool firstc = (c & (GS - 1)) == 0;

    __shared__ __align__(16) unsigned short R[17408];   // 34816 B, phase-shared
    __shared__ float rowf[BT], colf[BT], sfqs[BT], emcs[BT], denb[BT], npv[Ksz];

    auto khi = (unsigned short(*)[136])R;
    auto klo = (unsigned short(*)[136])(R + 64 * 136);
    auto Sb  = (unsigned short(*)[72])R;
    unsigned short* vTf = R + 64 * 72;
    unsigned short* cpsF = R;

    size_t hb = (size_t)bh * Tsz + (size_t)c * BT;
    float mpc = mp[bh * (NT + 1) + c];
    float pd = pdec[bh * NT + c];
    if (tid < BT) {
        float b = vecB[hb + tid];
        float mc = fmaxf(mpc + b, mintra[hb + tid]);
        rowf[tid] = SCALE * exp2f(b - mc);
        colf[tid] = exp2f(vecI[hb + tid] - b);
        sfqs[tid] = SCALE * exp2f(b + mpc - mc);
        emcs[tid] = exp2f(-mc);
    }
    if (tid < Ksz)
        npv[tid] = npl[((size_t)bh * NT + c) * Ksz + tid]
                 + pd * nB[((size_t)bh * NG + grp) * Ksz + tid];

    // ---- phase 1: stage k hi/lo; q -> regs; v prefetch ----
    const float4* k4 = (const float4*)(kgl + hb * Ksz);
    for (int e = tid; e < BT * Ksz / 4; e += 256) {
        int i = e >> 5, c4 = (e & 31) * 4;
        float4 kv = k4[e];
        u16x4 h, l;
        h.x = f2bf(kv.x); l.x = f2bf(kv.x - bf2f(h.x));
        h.y = f2bf(kv.y); l.y = f2bf(kv.y - bf2f(h.y));
        h.z = f2bf(kv.z); l.z = f2bf(kv.z - bf2f(h.z));
        h.w = f2bf(kv.w); l.w = f2bf(kv.w - bf2f(h.w));
        *(u16x4*)&khi[i][c4] = h; *(u16x4*)&klo[i][c4] = l;
    }
    const float* qrow = qg + (hb + wid * 16 + lrow) * Ksz;
    float qf[4][8];
    #pragma unroll
    for (int ks = 0; ks < 4; ++ks) {
        float4 a = *(const float4*)(qrow + ks * 32 + kgrp * 8);
        float4 b = *(const float4*)(qrow + ks * 32 + kgrp * 8 + 4);
        qf[ks][0] = a.x; qf[ks][1] = a.y; qf[ks][2] = a.z; qf[ks][3] = a.w;
        qf[ks][4] = b.x; qf[ks][5] = b.y; qf[ks][6] = b.z; qf[ks][7] = b.w;
    }
    int vcb = tid & 15, jb = tid >> 4;
    float vpre[2][4][4];
    #pragma unroll
    for (int p = 0; p < 2; ++p)
        #pragma unroll
        for (int x = 0; x < 4; ++x) {
            float4 r4 = *(const float4*)(vg + (hb + jb * 4 + x) * Vsz + p * 64 + vcb * 4);
            vpre[p][x][0] = r4.x; vpre[p][x][1] = r4.y; vpre[p][x][2] = r4.z; vpre[p][x][3] = r4.w;
        }
    __syncthreads();

    // ---- phase 2: denominator inter part + S = q k^T (3-way split) ----
    float dot = 0.f;
    #pragma unroll
    for (int ks = 0; ks < 4; ++ks)
        #pragma unroll
        for (int x = 0; x < 8; ++x) dot += qf[ks][x] * npv[ks * 32 + kgrp * 8 + x];
    dot += __shfl_xor(dot, 16, 64);
    dot += __shfl_xor(dot, 32, 64);
    float qdot = sfqs[wid * 16 + lrow] * dot;

    short8v qh[4], ql[4];
    #pragma unroll
    for (int ks = 0; ks < 4; ++ks)
        #pragma unroll
        for (int x = 0; x < 8; ++x) {
            float f = qf[ks][x];
            unsigned short hh = f2bf(f);
            qh[ks][x] = (short)hh;
            ql[ks][x] = (short)f2bf(f - bf2f(hh));
        }

    f32x4 accS[4];
    #pragma unroll
    for (int jt = 0; jt < 4; ++jt) accS[jt] = (f32x4){0.f, 0.f, 0.f, 0.f};
    #pragma unroll
    for (int ks = 0; ks < 4; ++ks) {
        #pragma unroll
        for (int jt = 0; jt < 4; ++jt) {
            if (jt <= wid) {
                short8v bh_ = *(const short8v*)&khi[jt * 16 + lrow][ks * 32 + kgrp * 8];
                short8v bl  = *(const short8v*)&klo[jt * 16 + lrow][ks * 32 + kgrp * 8];
                accS[jt] = __builtin_amdgcn_mfma_f32_16x16x32_bf16(qh[ks], bh_, accS[jt], 0, 0, 0);
                accS[jt] = __builtin_amdgcn_mfma_f32_16x16x32_bf16(ql[ks], bh_, accS[jt], 0, 0, 0);
                accS[jt] = __builtin_amdgcn_mfma_f32_16x16x32_bf16(qh[ks], bl,  accS[jt], 0, 0, 0);
            }
        }
    }

    float rsum[4] = {0.f, 0.f, 0.f, 0.f};
    unsigned short sreg[4][4];
    #pragma unroll
    for (int jt = 0; jt < 4; ++jt)
        #pragma unroll
        for (int r = 0; r < 4; ++r) {
            int i = wid * 16 + kgrp * 4 + r, j = jt * 16 + lrow;
            float val = (j <= i) ? accS[jt][r] * rowf[i] * colf[j] : 0.f;
            rsum[r] += val;
            sreg[jt][r] = f2bf(val);
        }
    #pragma unroll
    for (int r = 0; r < 4; ++r) {
        rsum[r] += __shfl_xor(rsum[r], 1, 64);
        rsum[r] += __shfl_xor(rsum[r], 2, 64);
        rsum[r] += __shfl_xor(rsum[r], 4, 64);
        rsum[r] += __shfl_xor(rsum[r], 8, 64);
    }
    float qd[4];
    #pragma unroll
    for (int r = 0; r < 4; ++r) qd[r] = __shfl(qdot, kgrp * 4 + r, 64);
    if (lrow == 0) {
        #pragma unroll
        for (int r = 0; r < 4; ++r) {
            int i = wid * 16 + kgrp * 4 + r;
            float den = qd[r] + rsum[r];
            denb[i] = 1.f / fmaxf(fabsf(den), emcs[i]);
        }
    }
    __syncthreads();   // phase-A reads of khi/klo complete

    // ---- phase 3: issue Cp/B loads; write Sb + swizzled vT ----
    const u16x8* Cg = (const u16x8*)(CpL + ((size_t)bh * NT + c) * (Ksz * Vsz));
    const u16x8* Bg = (const u16x8*)(Bb + ((size_t)bh * NG + grp) * (Ksz * Vsz));
    u16x8 cpre[8], bpre[8];
    #pragma unroll
    for (int p2 = 0; p2 < 8; ++p2) bpre[p2] = Bg[tid + p2 * 256];
    if (!firstc) {
        #pragma unroll
        for (int p2 = 0; p2 < 8; ++p2) cpre[p2] = Cg[tid + p2 * 256];
    }

    #pragma unroll
    for (int jt = 0; jt < 4; ++jt)
        #pragma unroll
        for (int r = 0; r < 4; ++r)
            Sb[wid * 16 + kgrp * 4 + r][jt * 16 + lrow] = sreg[jt][r];
    #pragma unroll
    for (int p = 0; p < 2; ++p)
        #pragma unroll
        for (int y = 0; y < 4; ++y) {
            int row = p * 64 + vcb * 4 + y;
            int swzb = (jb * 8) ^ ((row & 7) << 4);
            u16x4 w;
            #pragma unroll
            for (int x = 0; x < 4; ++x) w[x] = f2bf(vpre[p][x][y]);
            *(u16x4*)((char*)(vTf + row * 64) + swzb) = w;
        }
    __syncthreads();

    // ---- phase 4: PV = S @ v ----
    f32x4 accV[8];
    #pragma unroll
    for (int vt = 0; vt < 8; ++vt) accV[vt] = (f32x4){0.f, 0.f, 0.f, 0.f};
    #pragma unroll
    for (int ks = 0; ks < 2; ++ks) {
        short8v as_ = *(const short8v*)&Sb[wid * 16 + lrow][ks * 32 + kgrp * 8];
        #pragma unroll
        for (int vt = 0; vt < 8; ++vt) {
            int row = vt * 16 + lrow;
            int swzb = ((ks * 64 + kgrp * 16)) ^ ((row & 7) << 4);
            short8v bv = *(const short8v*)((const char*)(vTf + row * 64) + swzb);
            accV[vt] = __builtin_amdgcn_mfma_f32_16x16x32_bf16(as_, bv, accV[vt], 0, 0, 0);
        }
    }
    __syncthreads();   // phase-B reads of Sb/vT complete

    // ---- phase 5: stage Cp_eff = Cp_loc + pd*B (or B exactly for group-first chunk) ----
    if (firstc) {
        #pragma unroll
        for (int p2 = 0; p2 < 8; ++p2) {
            int idx = tid + p2 * 256;
            *(u16x8*)&cpsF[idx * 8] = bpre[p2];   // pd==1, Cp_loc==0 -> Cp_eff = B
        }
    } else {
        #pragma unroll
        for (int p2 = 0; p2 < 8; ++p2) {
            int idx = tid + p2 * 256;
            u16x8 cv = cpre[p2], bv = bpre[p2];
            u16x8 w;
            #pragma unroll
            for (int e = 0; e < 8; ++e) w[e] = f2bf(bf2f(cv[e]) + pd * bf2f(bv[e]));
            *(u16x8*)&cpsF[idx * 8] = w;
        }
    }
    __syncthreads();

    // ---- phase 6: inter = q @ Cp_eff + combine + store ----
    f32x4 accC[8];
    #pragma unroll
    for (int vt = 0; vt < 8; ++vt) accC[vt] = (f32x4){0.f, 0.f, 0.f, 0.f};
    #pragma unroll
    for (int ks = 0; ks < 4; ++ks) {
        int ktile = ks * 2 + (kgrp >> 1);
        int lsrc = (kgrp & 1) * 32 + lrow;
        #pragma unroll
        for (int vt = 0; vt < 8; ++vt) {
            const unsigned short* pf = &cpsF[((ktile * 8 + vt) * 64 + lsrc) * 4];
            u16x4 lo4 = *(const u16x4*)pf;
            u16x4 hi4 = *(const u16x4*)(pf + 64);
            short8v bc;
            bc[0] = (short)lo4.x; bc[1] = (short)lo4.y; bc[2] = (short)lo4.z; bc[3] = (short)lo4.w;
            bc[4] = (short)hi4.x; bc[5] = (short)hi4.y; bc[6] = (short)hi4.z; bc[7] = (short)hi4.w;
            accC[vt] = __builtin_amdgcn_mfma_f32_16x16x32_bf16(qh[ks], bc, accC[vt], 0, 0, 0);
            accC[vt] = __builtin_amdgcn_mfma_f32_16x16x32_bf16(ql[ks], bc, accC[vt], 0, 0, 0);
        }
    }
    size_t gb = hb * Vsz;
    #pragma unroll
    for (int vt = 0; vt < 8; ++vt)
        #pragma unroll
        for (int r = 0; r < 4; ++r) {
            int i = wid * 16 + kgrp * 4 + r, vc = vt * 16 + lrow;
            out[gb + (size_t)i * Vsz + vc] = (sfqs[i] * accC[vt][r] + accV[vt][r]) * denb[i];
        }
}

extern "C" void kernel_launch(void* const* d_in, const int* in_sizes, int n_in,
                              void* d_out, int out_size, void* d_ws, size_t ws_size,
                              hipStream_t stream) {
    const float* q  = (const float*)d_in[0];
    const float* k  = (const float*)d_in[1];
    const float* v  = (const float*)d_in[2];
    const float* ig = (const float*)d_in[3];
    const float* fg = (const float*)d_in[4];
    float* out = (float*)d_out;

    float* ws = (float*)d_ws;
    float* vecB   = ws;                       // BH*T
    float* vecI   = vecB + BH * Tsz;          // BH*T
    float* vecA   = vecI + BH * Tsz;          // BH*T
    float* mintra = vecA + BH * Tsz;          // BH*T
    float* scaG   = mintra + BH * Tsz;        // BH*NT
    float* scaA   = scaG + BH * NT;           // BH*NT
    float* dec    = scaA + BH * NT;           // BH*NT
    float* pdec   = dec + BH * NT;            // BH*NT
    float* decG   = pdec + BH * NT;           // BH*NG
    float* mp     = decG + BH * NG;           // BH*(NT+1)
    float* npl    = mp + BH * (NT + 1);       // BH*NT*K
    float* nG     = npl + BH * NT * Ksz;      // BH*NG*K
    unsigned short* CpL = (unsigned short*)(nG + BH * NG * Ksz);  // BH*NT*K*V bf16
    unsigned short* Gb  = CpL + (size_t)BH * NT * Ksz * Vsz;      // BH*NG*K*V bf16

    k_gates<<<dim3(NT, BH), 64, 0, stream>>>(ig, fg, vecB, vecI, vecA, mintra, scaG, scaA);
    k_mscan<<<dim3(BH), 64, 0, stream>>>(scaG, scaA, mp, dec, pdec, decG);
    k_state<<<dim3(NG, BH, 2), 256, 0, stream>>>(k, v, vecA, mp, dec, CpL, Gb, npl, nG);
    k_gscan<<<dim3(33, BH), 128, 0, stream>>>(Gb, nG, decG);
    k_intra<<<dim3(NT, BH), 256, 0, stream>>>(q, k, v, vecB, vecI, mintra, mp,
                                              npl, nG, CpL, Gb, pdec, out);
}